// Round 3
// baseline (283.003 us; speedup 1.0000x reference)
//
#include <hip/hip_runtime.h>

typedef unsigned short u16;
typedef __attribute__((ext_vector_type(8))) short bf16x8;   // 8 bf16 = 4 VGPRs
typedef __attribute__((ext_vector_type(4))) float f32x4;

#define B_   2
#define S_   2048
#define HID_ 1024
#define NH_  16
#define HD_  64
#define SCALE_ 0.125f    // 1/sqrt(64)

__device__ __forceinline__ u16 f2bf(float f) {
    union { float f; unsigned int i; } v; v.f = f;
    unsigned int r = v.i + 0x7fffu + ((v.i >> 16) & 1u);   // RNE
    return (u16)(r >> 16);
}
__device__ __forceinline__ bf16x8 ld8(const u16* p) {
    return *reinterpret_cast<const bf16x8*>(p);
}
// packed fp32x2 -> bf16x2 (RNE), src0 in low half
__device__ __forceinline__ unsigned cvtpk(float lo, float hi) {
    unsigned r;
    asm("v_cvt_pk_bf16_f32 %0, %1, %2" : "=v"(r) : "v"(lo), "v"(hi));
    return r;
}
// async global->LDS, 16B per lane; l must be wave-uniform (HW adds lane*16)
__device__ __forceinline__ void gll16(const u16* g, const u16* l) {
    __builtin_amdgcn_global_load_lds(
        (const __attribute__((address_space(1))) unsigned int*)g,
        (__attribute__((address_space(3))) unsigned int*)l, 16, 0, 0);
}

// ---------------------------------------------------------------------------
// Stage 0a: fp32 -> bf16 arena for X (4M elems) and Wq|Wk|Wv (3x1M elems).
// ---------------------------------------------------------------------------
__global__ __launch_bounds__(256) void convert_bf16(
    const float* __restrict__ X, const float* __restrict__ W0,
    const float* __restrict__ W1, const float* __restrict__ W2,
    u16* __restrict__ Xb, u16* __restrict__ Wb)
{
    const size_t s = (size_t)blockIdx.x * 256 + threadIdx.x;
    const float* src; u16* dst; size_t off;
    if (s < 524288) { src = X; dst = Xb; off = s * 8; }
    else {
        const size_t t = s - 524288;
        const int w = (int)(t >> 17);
        off = (t & 131071) * 8;
        src = w == 0 ? W0 : w == 1 ? W1 : W2;
        dst = Wb + (size_t)w * 1048576;
    }
    f32x4 a = *(const f32x4*)(src + off);
    f32x4 b = *(const f32x4*)(src + off + 4);
    bf16x8 r;
    #pragma unroll
    for (int e = 0; e < 4; e++) { r[e] = (short)f2bf(a[e]); r[4 + e] = (short)f2bf(b[e]); }
    *(bf16x8*)(dst + off) = r;
}

// ---------------------------------------------------------------------------
// Stage 0b: mask scan — flag=1 iff any mask value is nonzero (ignoring -0.0).
// ---------------------------------------------------------------------------
__global__ __launch_bounds__(256) void mask_scan(
    const unsigned* __restrict__ m, unsigned* __restrict__ flag)
{
    const size_t i = ((size_t)blockIdx.x * 256 + threadIdx.x) * 8;
    const uint4* p = (const uint4*)(m + i);
    uint4 a = p[0], b = p[1];
    const unsigned M = 0x7fffffffu;
    unsigned v = (a.x & M) | (a.y & M) | (a.z & M) | (a.w & M)
               | (b.x & M) | (b.y & M) | (b.z & M) | (b.w & M);
    if (v) atomicOr(flag, 1u);
}

// ---------------------------------------------------------------------------
// Stage 1: Y = Xb @ Wb^T + bias. Double-buffered global_load_lds pipeline
// (T3 minimum 2-phase): stage next K-tile at loop top, compute current, one
// barrier per iter — the mandatory pre-barrier vmcnt(0) drain now lands after
// a full tile of MFMA instead of immediately after issue.
// Epilogue bounces C through LDS for vectorized 16B stores; V is written
// transposed ([b,h,d,s]) so attention can stage V^T with row copies.
// ---------------------------------------------------------------------------
#define BK_ 32

__global__ __launch_bounds__(256) void qkv_mfma(
    const u16* __restrict__ Xb, const u16* __restrict__ Wb,
    const float* __restrict__ bq, const float* __restrict__ bk,
    const float* __restrict__ bv,
    u16* __restrict__ Q, u16* __restrict__ K, u16* __restrict__ V)
{
    __shared__ __align__(16) u16 As[2][128 * BK_];   // 2 x 8 KB
    __shared__ __align__(16) u16 Bs[2][128 * BK_];   // 2 x 8 KB

    const int tid  = threadIdx.x;
    const int wave = tid >> 6;
    const int lane = tid & 63;
    const int l16  = lane & 15;
    const int quad = lane >> 4;
    const int wr   = wave >> 1, wc = wave & 1;

    const int i0 = blockIdx.x * 128;
    const int j0 = blockIdx.y * 128;

    // gll geometry: chunk c = tid covers u16 [c*8, c*8+8) of the half-tile
    const int grow = tid >> 2;                      // 0..63
    const int gcol = (lane & 3) * 8;

    f32x4 acc[4][4] = {};

    auto stage = [&](int bf, int k0) {
        gll16(Xb + (size_t)(i0 + grow) * HID_ + k0 + gcol, &As[bf][wave * 512]);
        gll16(Xb + (size_t)(i0 + 64 + grow) * HID_ + k0 + gcol, &As[bf][2048 + wave * 512]);
        gll16(Wb + (size_t)(j0 + grow) * HID_ + k0 + gcol, &Bs[bf][wave * 512]);
        gll16(Wb + (size_t)(j0 + 64 + grow) * HID_ + k0 + gcol, &Bs[bf][2048 + wave * 512]);
    };

    stage(0, 0);
    __syncthreads();

    for (int t = 0; t < 32; t++) {
        const int cur = t & 1;
        if (t < 31) stage(cur ^ 1, (t + 1) * BK_);   // issue early; drains at barrier

        bf16x8 af[4], bfr[4];
        #pragma unroll
        for (int mt = 0; mt < 4; mt++)
            af[mt] = ld8(&As[cur][(wr * 64 + mt * 16 + l16) * BK_ + quad * 8]);
        #pragma unroll
        for (int nt = 0; nt < 4; nt++)
            bfr[nt] = ld8(&Bs[cur][(wc * 64 + nt * 16 + l16) * BK_ + quad * 8]);
        #pragma unroll
        for (int mt = 0; mt < 4; mt++)
            #pragma unroll
            for (int nt = 0; nt < 4; nt++)
                acc[mt][nt] = __builtin_amdgcn_mfma_f32_16x16x32_bf16(af[mt], bfr[nt], acc[mt][nt], 0, 0, 0);

        __syncthreads();
    }

    const int which = j0 >> 10;                     // block-uniform
    const float* bias = which == 0 ? bq : which == 1 ? bk : bv;
    u16* Y            = which == 0 ? Q  : which == 1 ? K  : V;

    // bounce buffer: 4 waves x 2048 u16 (4 KB each) reusing buffer-0 halves
    u16* bb = (wave < 2) ? &As[0][wave * 2048] : &Bs[0][(wave - 2) * 2048];

    #pragma unroll
    for (int p = 0; p < 2; p++) {
        __syncthreads();
        // write phase: 64x32 wave tile (rows = m, cols = p*32..p*32+31)
        #pragma unroll
        for (int t2 = 0; t2 < 2; t2++) {
            const int nt = 2 * p + t2;
            const int j  = j0 + wc * 64 + nt * 16 + l16;
            const int jj = j & 1023;
            const float bv_ = bias[jj];
            #pragma unroll
            for (int mt = 0; mt < 4; mt++)
                #pragma unroll
                for (int r = 0; r < 4; r++) {
                    const int row = mt * 16 + quad * 4 + r;   // 0..63
                    const int col = t2 * 16 + l16;            // 0..31
                    const u16 val = f2bf(acc[mt][nt][r] + bv_);
                    if (which == 2)
                        bb[col * 64 + (row ^ ((col & 7) << 3))] = val;      // transposed
                    else
                        bb[row * 32 + (col ^ ((row & 0xC) << 1))] = val;    // row-major
                }
        }
        __syncthreads();
        // read + vector-store phase: 4 x 16B chunks per thread
        #pragma unroll
        for (int k = 0; k < 4; k++) {
            const int c = lane + 64 * k;   // 0..255 chunks of this wave's 4 KB
            if (which == 2) {
                const int col  = c >> 3;                 // d-col 0..31
                const int row0 = (c & 7) * 8;            // s-rows row0..row0+7
                bf16x8 v = ld8(&bb[col * 64 + (row0 ^ ((col & 7) << 3))]);
                const int j  = j0 + wc * 64 + p * 32 + col;
                const int jj = j & 1023;
                const int h = jj >> 6, d = jj & 63;
                const int i = i0 + wr * 64 + row0;
                const int b = i >> 11, s = i & (S_ - 1);
                *(bf16x8*)&Y[((size_t)(b * NH_ + h) * HD_ + d) * S_ + s] = v;
            } else {
                const int row  = c >> 2;                 // m-row 0..63
                const int col0 = (c & 3) * 8;            // cols col0..col0+7
                bf16x8 v = ld8(&bb[row * 32 + (col0 ^ ((row & 0xC) << 1))]);
                const int j  = j0 + wc * 64 + p * 32 + col0;
                const int jj = j & 1023;
                const int h = jj >> 6, d = jj & 63;
                const int i = i0 + wr * 64 + row;
                const int b = i >> 11, s = i & (S_ - 1);
                *(bf16x8*)&Y[(((size_t)(b * NH_ + h) * S_ + s) * HD_) + d] = v;
            }
        }
    }
}

// ---------------------------------------------------------------------------
// Stage 2: attention. Block = 4 waves, one (b,h), 64 q rows; wave = 16 rows.
// Double-buffered K/V^T tiles in LDS (XOR-swizzled), reg-staged 2-phase
// pipeline. Deferred softmax (p = exp(min(s,80)), one reduction at end).
// P bf16 conversion via v_cvt_pk_bf16_f32 (half the VALU of manual RNE).
// Probs: p_unnorm stored in-loop for qb>=30; the same blocks rescale their
// own 128 rows in place after the loop (L2-resident) — no finisher kernel.
// s_setprio(1) around MFMA clusters (T5, +4-7% on attn).
// ---------------------------------------------------------------------------
__global__ __launch_bounds__(256) void attn(
    const u16* __restrict__ Q, const u16* __restrict__ K, const u16* __restrict__ Vt,
    const float* __restrict__ mask, const float* __restrict__ hw,
    const unsigned* __restrict__ mflag,
    float* __restrict__ ctx, float* __restrict__ probs_out)
{
    __shared__ __align__(16) u16 Ks[2][64 * 64];   // 16 KB  [key][d], swizzled
    __shared__ __align__(16) u16 Vs[2][64 * 64];   // 16 KB  [d][key], swizzled
    __shared__ __align__(16) u16 Pl[4][16 * 64];   //  8 KB  per-wave P, swizzled

    const int usemask = (mflag[0] != 0);

    const int tid  = threadIdx.x;
    const int wave = tid >> 6;
    const int lane = tid & 63;
    const int l16  = lane & 15;
    const int quad = lane >> 4;
    const int x7   = l16 & 7;

    // XCD-aware remap: 4 whole (b,h) per XCD so K/V^T stay L2-resident.
    const int lin = blockIdx.x + 32 * (blockIdx.y + 16 * blockIdx.z);
    const int xcd = lin & 7, jj = lin >> 3;
    const int qb  = jj & 31;
    const int hb  = xcd * 4 + (jj >> 5);
    const int h   = hb & 15, b = hb >> 4;
    const int bh  = b * NH_ + h;

    const u16* Qh  = Q  + (size_t)bh * S_ * HD_;
    const u16* Kh  = K  + (size_t)bh * S_ * HD_;
    const u16* Vth = Vt + (size_t)bh * HD_ * S_;   // [d][s]
    const float* Mb = mask + (size_t)b * S_ * S_;

    const int q0 = qb * 64 + wave * 16;

    bf16x8 qf0 = ld8(Qh + (size_t)(q0 + l16) * HD_ + quad * 8);
    bf16x8 qf1 = ld8(Qh + (size_t)(q0 + l16) * HD_ + 32 + quad * 8);

    f32x4 oacc[4] = {};
    float l_part[4] = {0.f, 0.f, 0.f, 0.f};

    // staging geometry: thread covers 16B slots {tid, tid+256} of each tile
    const int srow = tid >> 3;
    const int sch  = tid & 7;
    const int ssw  = (sch ^ (srow & 7)) * 8;
    const int sL   = srow * 64 + ssw;

    {   // prologue: stage tile 0
        bf16x8 k0 = ld8(Kh + (size_t)srow * HD_ + sch * 8);
        bf16x8 k1 = ld8(Kh + (size_t)(srow + 32) * HD_ + sch * 8);
        bf16x8 v0 = ld8(Vth + (size_t)srow * S_ + sch * 8);
        bf16x8 v1 = ld8(Vth + (size_t)(srow + 32) * S_ + sch * 8);
        *(bf16x8*)&Ks[0][sL] = k0; *(bf16x8*)&Ks[0][sL + 2048] = k1;
        *(bf16x8*)&Vs[0][sL] = v0; *(bf16x8*)&Vs[0][sL + 2048] = v1;
    }
    __syncthreads();

    for (int t = 0; t < 32; ++t) {
        const int cur = t & 1;
        const int kt  = t * 64;
        const u16* Kb = Ks[cur];
        const u16* Vb = Vs[cur];

        // issue next-tile global loads EARLY
        bf16x8 kr0, kr1, vr0, vr1;
        if (t < 31) {
            const u16* Kg = Kh + (size_t)(kt + 64) * HD_;
            kr0 = ld8(Kg + (size_t)srow * HD_ + sch * 8);
            kr1 = ld8(Kg + (size_t)(srow + 32) * HD_ + sch * 8);
            vr0 = ld8(Vth + (size_t)srow * S_ + kt + 64 + sch * 8);
            vr1 = ld8(Vth + (size_t)(srow + 32) * S_ + kt + 64 + sch * 8);
        }

        // --- S = Q K^T (scaled below) ---
        f32x4 sacc[4] = {};
        __builtin_amdgcn_s_setprio(1);
        #pragma unroll
        for (int nb = 0; nb < 4; nb++) {
            const int base = (nb * 16 + l16) * 64;
            bf16x8 k0 = ld8(&Kb[base + ((quad ^ x7) * 8)]);
            bf16x8 k1 = ld8(&Kb[base + (((quad + 4) ^ x7) * 8)]);
            sacc[nb] = __builtin_amdgcn_mfma_f32_16x16x32_bf16(qf0, k0, sacc[nb], 0, 0, 0);
            sacc[nb] = __builtin_amdgcn_mfma_f32_16x16x32_bf16(qf1, k1, sacc[nb], 0, 0, 0);
        }
        __builtin_amdgcn_s_setprio(0);

        // --- deferred softmax: p = exp(min(s,80)), per-lane l accumulation ---
        float p[4][4];
        if (usemask) {
            #pragma unroll
            for (int nb = 0; nb < 4; nb++)
                #pragma unroll
                for (int r = 0; r < 4; r++) {
                    const int qrow = q0 + quad * 4 + r;
                    const int key  = kt + nb * 16 + l16;
                    float s = sacc[nb][r] * SCALE_ + Mb[(size_t)qrow * S_ + key];
                    p[nb][r] = __expf(fminf(s, 80.f));
                    l_part[r] += p[nb][r];
                }
        } else {
            #pragma unroll
            for (int nb = 0; nb < 4; nb++)
                #pragma unroll
                for (int r = 0; r < 4; r++) {
                    p[nb][r] = __expf(fminf(sacc[nb][r] * SCALE_, 80.f));
                    l_part[r] += p[nb][r];
                }
        }

        // unnormalized probs for last CHUNK rows — rescaled in the tail
        if (qb >= 30) {
            #pragma unroll
            for (int nb = 0; nb < 4; nb++)
                #pragma unroll
                for (int r = 0; r < 4; r++) {
                    const int qrow = q0 + quad * 4 + r;
                    const int key  = kt + nb * 16 + l16;
                    probs_out[((size_t)bh * 128 + (qrow - 1920)) * S_ + key] = p[nb][r];
                }
        }

        // --- P -> bf16 (cvt_pk) -> per-wave LDS (swizzled; wave-local) ---
        {
            char* pbase = (char*)&Pl[wave][0];
            const int r0 = quad * 4;
            #pragma unroll
            for (int nb = 0; nb < 4; nb++) {
                const unsigned w01 = cvtpk(p[nb][0], p[nb][1]);
                const unsigned w23 = cvtpk(p[nb][2], p[nb][3]);
                const int c0 = nb * 32 + l16 * 2;
                *(u16*)(pbase + (r0 + 0) * 128 + (c0 ^ (((r0 + 0) & 7) << 4))) = (u16)w01;
                *(u16*)(pbase + (r0 + 1) * 128 + (c0 ^ (((r0 + 1) & 7) << 4))) = (u16)(w01 >> 16);
                *(u16*)(pbase + (r0 + 2) * 128 + (c0 ^ (((r0 + 2) & 7) << 4))) = (u16)w23;
                *(u16*)(pbase + (r0 + 3) * 128 + (c0 ^ (((r0 + 3) & 7) << 4))) = (u16)(w23 >> 16);
            }
        }

        // --- O += P @ V ---
        __builtin_amdgcn_s_setprio(1);
        #pragma unroll
        for (int kb = 0; kb < 2; kb++) {
            const int c = kb * 4 + quad;
            bf16x8 pf = ld8(&Pl[wave][l16 * 64 + ((c ^ x7) * 8)]);
            #pragma unroll
            for (int db = 0; db < 4; db++) {
                bf16x8 vf = ld8(&Vb[(db * 16 + l16) * 64 + ((c ^ x7) * 8)]);
                oacc[db] = __builtin_amdgcn_mfma_f32_16x16x32_bf16(pf, vf, oacc[db], 0, 0, 0);
            }
        }
        __builtin_amdgcn_s_setprio(0);

        // --- write next tile to the other buffer, then sync ---
        if (t < 31) {
            u16* Kd = Ks[cur ^ 1]; u16* Vd = Vs[cur ^ 1];
            *(bf16x8*)&Kd[sL] = kr0; *(bf16x8*)&Kd[sL + 2048] = kr1;
            *(bf16x8*)&Vd[sL] = vr0; *(bf16x8*)&Vd[sL + 2048] = vr1;
        }
        __syncthreads();
    }

    // --- ONE cross-lane reduction of the denominator (16 lanes) ---
    float l_i[4];
    #pragma unroll
    for (int r = 0; r < 4; r++) {
        float s = l_part[r];
        #pragma unroll
        for (int off = 1; off < 16; off <<= 1) s += __shfl_xor(s, off);
        l_i[r] = s;
    }

    // --- epilogue: context ---
    const float hwf = hw[h];
    float invl[4];
    #pragma unroll
    for (int r = 0; r < 4; r++) invl[r] = hwf / l_i[r];

    #pragma unroll
    for (int db = 0; db < 4; db++)
        #pragma unroll
        for (int r = 0; r < 4; r++) {
            const int qrow = q0 + quad * 4 + r;
            ctx[((size_t)(b * S_ + qrow)) * HID_ + h * HD_ + db * 16 + l16] =
                oacc[db][r] * invl[r];
        }

    // --- probs tail: rescale own rows in place (L2-resident round trip) ---
    if (qb >= 30) {
        __threadfence();   // drain + invalidate L1 so re-reads see our stores
        #pragma unroll
        for (int r = 0; r < 4; r++) {
            const int prow = q0 - 1920 + quad * 4 + r;
            float4* P4 = (float4*)(probs_out + ((size_t)bh * 128 + prow) * S_);
            const float sc = invl[r];
            for (int i = l16; i < 512; i += 16) {
                float4 v = P4[i];
                v.x *= sc; v.y *= sc; v.z *= sc; v.w *= sc;
                P4[i] = v;
            }
        }
    }
}

// ---------------------------------------------------------------------------
extern "C" void kernel_launch(void* const* d_in, const int* in_sizes, int n_in,
                              void* d_out, int out_size, void* d_ws, size_t ws_size,
                              hipStream_t stream)
{
    const void* X = 0; const void* mask = 0; const void* hw = 0;
    const void* Wm[3] = {0, 0, 0}; const void* bm[3] = {0, 0, 0};
    int wi = 0, bi = 0;
    for (int i = 0; i < n_in; i++) {
        switch (in_sizes[i]) {
            case 4194304: X = d_in[i]; break;
            case 8388608: mask = d_in[i]; break;
            case 1048576: if (wi < 3) Wm[wi++] = d_in[i]; break;
            case 1024:    if (bi < 3) bm[bi++] = d_in[i]; break;
            case 16:      hw = d_in[i]; break;
            default: break;
        }
    }
    if (!X || !mask || wi != 3 || bi != 3 || !hw) {
        X = d_in[0]; mask = d_in[1];
        Wm[0] = d_in[2]; bm[0] = d_in[3];
        Wm[1] = d_in[4]; bm[1] = d_in[5];
        Wm[2] = d_in[6]; bm[2] = d_in[7];
        hw = d_in[8];
    }

    u16* Q  = (u16*)d_ws;                    // 8 MB
    u16* Kw = Q + 4194304ull;                // 8 MB
    u16* Vw = Kw + 4194304ull;               // 8 MB (stored transposed per head)
    u16* Xb = Vw + 4194304ull;               // 8 MB
    u16* Wb = Xb + 4194304ull;               // 6 MB
    unsigned* flag = (unsigned*)(Wb + 3145728ull);   // 4 B @ 38 MB

    float* ctx   = (float*)d_out;
    float* probs = ctx + (size_t)B_ * S_ * HID_;

    hipMemsetAsync(flag, 0, 4, stream);
    mask_scan<<<4096, 256, 0, stream>>>((const unsigned*)mask, flag);
    convert_bf16<<<3584, 256, 0, stream>>>(
        (const float*)X, (const float*)Wm[0], (const float*)Wm[1], (const float*)Wm[2],
        Xb, Wb);

    qkv_mfma<<<dim3(32, 24), dim3(256), 0, stream>>>(
        Xb, Wb, (const float*)bm[0], (const float*)bm[1], (const float*)bm[2],
        Q, Kw, Vw);

    attn<<<dim3(32, 16, 2), dim3(256), 0, stream>>>(
        Q, Kw, Vw, (const float*)mask, (const float*)hw, flag, ctx, probs);
}

// Round 4
// 248.837 us; speedup vs baseline: 1.1373x; 1.1373x over previous
//
#include <hip/hip_runtime.h>

typedef unsigned short u16;
typedef __attribute__((ext_vector_type(8))) short bf16x8;   // 8 bf16 = 4 VGPRs
typedef __attribute__((ext_vector_type(4))) float f32x4;

#define B_   2
#define S_   2048
#define HID_ 1024
#define NH_  16
#define HD_  64
#define SCALE_ 0.125f    // 1/sqrt(64)

__device__ __forceinline__ u16 f2bf(float f) {
    union { float f; unsigned int i; } v; v.f = f;
    unsigned int r = v.i + 0x7fffu + ((v.i >> 16) & 1u);   // RNE
    return (u16)(r >> 16);
}
__device__ __forceinline__ bf16x8 ld8(const u16* p) {
    return *reinterpret_cast<const bf16x8*>(p);
}
// packed fp32x2 -> bf16x2 (RNE), src0 in low half
__device__ __forceinline__ unsigned cvtpk(float lo, float hi) {
    unsigned r;
    asm("v_cvt_pk_bf16_f32 %0, %1, %2" : "=v"(r) : "v"(lo), "v"(hi));
    return r;
}
// async global->LDS, 16B per lane; l must be wave-uniform (HW adds lane*16)
__device__ __forceinline__ void gll16(const u16* g, const u16* l) {
    __builtin_amdgcn_global_load_lds(
        (const __attribute__((address_space(1))) unsigned int*)g,
        (__attribute__((address_space(3))) unsigned int*)l, 16, 0, 0);
}

// ---------------------------------------------------------------------------
// Stage 0a: fp32 -> bf16 arena for X (4M elems) and Wq|Wk|Wv (3x1M elems).
// ---------------------------------------------------------------------------
__global__ __launch_bounds__(256) void convert_bf16(
    const float* __restrict__ X, const float* __restrict__ W0,
    const float* __restrict__ W1, const float* __restrict__ W2,
    u16* __restrict__ Xb, u16* __restrict__ Wb)
{
    const size_t s = (size_t)blockIdx.x * 256 + threadIdx.x;
    const float* src; u16* dst; size_t off;
    if (s < 524288) { src = X; dst = Xb; off = s * 8; }
    else {
        const size_t t = s - 524288;
        const int w = (int)(t >> 17);
        off = (t & 131071) * 8;
        src = w == 0 ? W0 : w == 1 ? W1 : W2;
        dst = Wb + (size_t)w * 1048576;
    }
    f32x4 a = *(const f32x4*)(src + off);
    f32x4 b = *(const f32x4*)(src + off + 4);
    bf16x8 r;
    #pragma unroll
    for (int e = 0; e < 4; e++) { r[e] = (short)f2bf(a[e]); r[4 + e] = (short)f2bf(b[e]); }
    *(bf16x8*)(dst + off) = r;
}

// ---------------------------------------------------------------------------
// Stage 0b: mask scan — flag=1 iff any mask value is nonzero (ignoring -0.0).
// ---------------------------------------------------------------------------
__global__ __launch_bounds__(256) void mask_scan(
    const unsigned* __restrict__ m, unsigned* __restrict__ flag)
{
    const size_t i = ((size_t)blockIdx.x * 256 + threadIdx.x) * 8;
    const uint4* p = (const uint4*)(m + i);
    uint4 a = p[0], b = p[1];
    const unsigned M = 0x7fffffffu;
    unsigned v = (a.x & M) | (a.y & M) | (a.z & M) | (a.w & M)
               | (b.x & M) | (b.y & M) | (b.z & M) | (b.w & M);
    if (v) atomicOr(flag, 1u);
}

// ---------------------------------------------------------------------------
// Stage 1: Y = Xb @ Wb^T + bias (R2 structure — single-buffered gll; the
// explicit dbuf variant regressed ~16 µs, m131-m141 lesson). Epilogue bounces
// C through LDS for 16B stores; V written transposed ([b,h,d,s]).
// ---------------------------------------------------------------------------
#define BK_ 32

__global__ __launch_bounds__(256) void qkv_mfma(
    const u16* __restrict__ Xb, const u16* __restrict__ Wb,
    const float* __restrict__ bq, const float* __restrict__ bk,
    const float* __restrict__ bv,
    u16* __restrict__ Q, u16* __restrict__ K, u16* __restrict__ V)
{
    __shared__ __align__(16) u16 As[128 * BK_];   // 8 KB, linear row-major
    __shared__ __align__(16) u16 Bs[128 * BK_];   // 8 KB

    const int tid  = threadIdx.x;
    const int wave = tid >> 6;
    const int lane = tid & 63;
    const int l16  = lane & 15;
    const int quad = lane >> 4;
    const int wr   = wave >> 1, wc = wave & 1;

    const int i0 = blockIdx.x * 128;
    const int j0 = blockIdx.y * 128;

    const int grow = (wave * 64 + lane) >> 2;       // 0..63
    const int gcol = (lane & 3) * 8;
    const u16* ldsA0 = As + wave * 512;             // wave-uniform bases
    const u16* ldsA1 = As + 2048 + wave * 512;
    const u16* ldsB0 = Bs + wave * 512;
    const u16* ldsB1 = Bs + 2048 + wave * 512;

    f32x4 acc[4][4] = {};

    for (int k0 = 0; k0 < HID_; k0 += BK_) {
        __syncthreads();
        gll16(Xb + (size_t)(i0 + grow) * HID_ + k0 + gcol, ldsA0);
        gll16(Xb + (size_t)(i0 + 64 + grow) * HID_ + k0 + gcol, ldsA1);
        gll16(Wb + (size_t)(j0 + grow) * HID_ + k0 + gcol, ldsB0);
        gll16(Wb + (size_t)(j0 + 64 + grow) * HID_ + k0 + gcol, ldsB1);
        __syncthreads();

        bf16x8 af[4], bfr[4];
        #pragma unroll
        for (int mt = 0; mt < 4; mt++)
            af[mt] = ld8(&As[(wr * 64 + mt * 16 + l16) * BK_ + quad * 8]);
        #pragma unroll
        for (int nt = 0; nt < 4; nt++)
            bfr[nt] = ld8(&Bs[(wc * 64 + nt * 16 + l16) * BK_ + quad * 8]);
        #pragma unroll
        for (int mt = 0; mt < 4; mt++)
            #pragma unroll
            for (int nt = 0; nt < 4; nt++)
                acc[mt][nt] = __builtin_amdgcn_mfma_f32_16x16x32_bf16(af[mt], bfr[nt], acc[mt][nt], 0, 0, 0);
    }

    const int which = j0 >> 10;                     // block-uniform
    const float* bias = which == 0 ? bq : which == 1 ? bk : bv;
    u16* Y            = which == 0 ? Q  : which == 1 ? K  : V;

    // bounce buffer: 4 waves x 2048 u16 (4 KB each) reusing As/Bs
    u16* bb = (wave < 2) ? (As + wave * 2048) : (Bs + (wave - 2) * 2048);

    #pragma unroll
    for (int p = 0; p < 2; p++) {
        __syncthreads();
        #pragma unroll
        for (int t2 = 0; t2 < 2; t2++) {
            const int nt = 2 * p + t2;
            const int j  = j0 + wc * 64 + nt * 16 + l16;
            const int jj = j & 1023;
            const float bv_ = bias[jj];
            #pragma unroll
            for (int mt = 0; mt < 4; mt++)
                #pragma unroll
                for (int r = 0; r < 4; r++) {
                    const int row = mt * 16 + quad * 4 + r;   // 0..63
                    const int col = t2 * 16 + l16;            // 0..31
                    const u16 val = f2bf(acc[mt][nt][r] + bv_);
                    if (which == 2)
                        bb[col * 64 + (row ^ ((col & 7) << 3))] = val;      // transposed
                    else
                        bb[row * 32 + (col ^ ((row & 0xC) << 1))] = val;    // row-major
                }
        }
        __syncthreads();
        #pragma unroll
        for (int k = 0; k < 4; k++) {
            const int c = lane + 64 * k;   // 0..255 chunks of this wave's 4 KB
            if (which == 2) {
                const int col  = c >> 3;
                const int row0 = (c & 7) * 8;
                bf16x8 v = ld8(&bb[col * 64 + (row0 ^ ((col & 7) << 3))]);
                const int j  = j0 + wc * 64 + p * 32 + col;
                const int jj = j & 1023;
                const int h = jj >> 6, d = jj & 63;
                const int i = i0 + wr * 64 + row0;
                const int b = i >> 11, s = i & (S_ - 1);
                *(bf16x8*)&Y[((size_t)(b * NH_ + h) * HD_ + d) * S_ + s] = v;
            } else {
                const int row  = c >> 2;
                const int col0 = (c & 3) * 8;
                bf16x8 v = ld8(&bb[row * 32 + (col0 ^ ((row & 0xC) << 1))]);
                const int j  = j0 + wc * 64 + p * 32 + col0;
                const int jj = j & 1023;
                const int h = jj >> 6, d = jj & 63;
                const int i = i0 + wr * 64 + row;
                const int b = i >> 11, s = i & (S_ - 1);
                *(bf16x8*)&Y[(((size_t)(b * NH_ + h) * S_ + s) * HD_) + d] = v;
            }
        }
    }
}

// ---------------------------------------------------------------------------
// Stage 2: attention — NO probs work (only per-row l saved for qb>=30).
// Double-buffered K/V^T tiles in LDS (XOR-swizzled), reg-staged 2-phase
// pipeline, deferred softmax, cvt_pk P conversion, setprio around MFMA.
// ---------------------------------------------------------------------------
__global__ __launch_bounds__(256) void attn(
    const u16* __restrict__ Q, const u16* __restrict__ K, const u16* __restrict__ Vt,
    const float* __restrict__ mask, const float* __restrict__ hw,
    const unsigned* __restrict__ mflag,
    float* __restrict__ ctx, float* __restrict__ ml)
{
    __shared__ __align__(16) u16 Ks[2][64 * 64];   // 16 KB  [key][d], swizzled
    __shared__ __align__(16) u16 Vs[2][64 * 64];   // 16 KB  [d][key], swizzled
    __shared__ __align__(16) u16 Pl[4][16 * 64];   //  8 KB  per-wave P, swizzled

    const int usemask = (mflag[0] != 0);

    const int tid  = threadIdx.x;
    const int wave = tid >> 6;
    const int lane = tid & 63;
    const int l16  = lane & 15;
    const int quad = lane >> 4;
    const int x7   = l16 & 7;

    // XCD-aware remap: 4 whole (b,h) per XCD so K/V^T stay L2-resident.
    const int lin = blockIdx.x + 32 * (blockIdx.y + 16 * blockIdx.z);
    const int xcd = lin & 7, jj = lin >> 3;
    const int qb  = jj & 31;
    const int hb  = xcd * 4 + (jj >> 5);
    const int h   = hb & 15, b = hb >> 4;
    const int bh  = b * NH_ + h;

    const u16* Qh  = Q  + (size_t)bh * S_ * HD_;
    const u16* Kh  = K  + (size_t)bh * S_ * HD_;
    const u16* Vth = Vt + (size_t)bh * HD_ * S_;   // [d][s]
    const float* Mb = mask + (size_t)b * S_ * S_;

    const int q0 = qb * 64 + wave * 16;

    bf16x8 qf0 = ld8(Qh + (size_t)(q0 + l16) * HD_ + quad * 8);
    bf16x8 qf1 = ld8(Qh + (size_t)(q0 + l16) * HD_ + 32 + quad * 8);

    f32x4 oacc[4] = {};
    float l_part[4] = {0.f, 0.f, 0.f, 0.f};

    // staging geometry: thread covers 16B slots {tid, tid+256} of each tile
    const int srow = tid >> 3;
    const int sch  = tid & 7;
    const int ssw  = (sch ^ (srow & 7)) * 8;
    const int sL   = srow * 64 + ssw;

    {   // prologue: stage tile 0
        bf16x8 k0 = ld8(Kh + (size_t)srow * HD_ + sch * 8);
        bf16x8 k1 = ld8(Kh + (size_t)(srow + 32) * HD_ + sch * 8);
        bf16x8 v0 = ld8(Vth + (size_t)srow * S_ + sch * 8);
        bf16x8 v1 = ld8(Vth + (size_t)(srow + 32) * S_ + sch * 8);
        *(bf16x8*)&Ks[0][sL] = k0; *(bf16x8*)&Ks[0][sL + 2048] = k1;
        *(bf16x8*)&Vs[0][sL] = v0; *(bf16x8*)&Vs[0][sL + 2048] = v1;
    }
    __syncthreads();

    for (int t = 0; t < 32; ++t) {
        const int cur = t & 1;
        const int kt  = t * 64;
        const u16* Kb = Ks[cur];
        const u16* Vb = Vs[cur];

        // issue next-tile global loads EARLY
        bf16x8 kr0, kr1, vr0, vr1;
        if (t < 31) {
            const u16* Kg = Kh + (size_t)(kt + 64) * HD_;
            kr0 = ld8(Kg + (size_t)srow * HD_ + sch * 8);
            kr1 = ld8(Kg + (size_t)(srow + 32) * HD_ + sch * 8);
            vr0 = ld8(Vth + (size_t)srow * S_ + kt + 64 + sch * 8);
            vr1 = ld8(Vth + (size_t)(srow + 32) * S_ + kt + 64 + sch * 8);
        }

        // --- S = Q K^T (scaled below) ---
        f32x4 sacc[4] = {};
        __builtin_amdgcn_s_setprio(1);
        #pragma unroll
        for (int nb = 0; nb < 4; nb++) {
            const int base = (nb * 16 + l16) * 64;
            bf16x8 k0 = ld8(&Kb[base + ((quad ^ x7) * 8)]);
            bf16x8 k1 = ld8(&Kb[base + (((quad + 4) ^ x7) * 8)]);
            sacc[nb] = __builtin_amdgcn_mfma_f32_16x16x32_bf16(qf0, k0, sacc[nb], 0, 0, 0);
            sacc[nb] = __builtin_amdgcn_mfma_f32_16x16x32_bf16(qf1, k1, sacc[nb], 0, 0, 0);
        }
        __builtin_amdgcn_s_setprio(0);

        // --- deferred softmax: p = exp(min(s,80)), per-lane l accumulation ---
        float p[4][4];
        if (usemask) {
            #pragma unroll
            for (int nb = 0; nb < 4; nb++)
                #pragma unroll
                for (int r = 0; r < 4; r++) {
                    const int qrow = q0 + quad * 4 + r;
                    const int key  = kt + nb * 16 + l16;
                    float s = sacc[nb][r] * SCALE_ + Mb[(size_t)qrow * S_ + key];
                    p[nb][r] = __expf(fminf(s, 80.f));
                    l_part[r] += p[nb][r];
                }
        } else {
            #pragma unroll
            for (int nb = 0; nb < 4; nb++)
                #pragma unroll
                for (int r = 0; r < 4; r++) {
                    p[nb][r] = __expf(fminf(sacc[nb][r] * SCALE_, 80.f));
                    l_part[r] += p[nb][r];
                }
        }

        // --- P -> bf16 (cvt_pk) -> per-wave LDS (swizzled; wave-local) ---
        {
            char* pbase = (char*)&Pl[wave][0];
            const int r0 = quad * 4;
            #pragma unroll
            for (int nb = 0; nb < 4; nb++) {
                const unsigned w01 = cvtpk(p[nb][0], p[nb][1]);
                const unsigned w23 = cvtpk(p[nb][2], p[nb][3]);
                const int c0 = nb * 32 + l16 * 2;
                *(u16*)(pbase + (r0 + 0) * 128 + (c0 ^ (((r0 + 0) & 7) << 4))) = (u16)w01;
                *(u16*)(pbase + (r0 + 1) * 128 + (c0 ^ (((r0 + 1) & 7) << 4))) = (u16)(w01 >> 16);
                *(u16*)(pbase + (r0 + 2) * 128 + (c0 ^ (((r0 + 2) & 7) << 4))) = (u16)w23;
                *(u16*)(pbase + (r0 + 3) * 128 + (c0 ^ (((r0 + 3) & 7) << 4))) = (u16)(w23 >> 16);
            }
        }

        // --- O += P @ V ---
        __builtin_amdgcn_s_setprio(1);
        #pragma unroll
        for (int kb = 0; kb < 2; kb++) {
            const int c = kb * 4 + quad;
            bf16x8 pf = ld8(&Pl[wave][l16 * 64 + ((c ^ x7) * 8)]);
            #pragma unroll
            for (int db = 0; db < 4; db++) {
                bf16x8 vf = ld8(&Vb[(db * 16 + l16) * 64 + ((c ^ x7) * 8)]);
                oacc[db] = __builtin_amdgcn_mfma_f32_16x16x32_bf16(pf, vf, oacc[db], 0, 0, 0);
            }
        }
        __builtin_amdgcn_s_setprio(0);

        // --- write next tile to the other buffer, then sync ---
        if (t < 31) {
            u16* Kd = Ks[cur ^ 1]; u16* Vd = Vs[cur ^ 1];
            *(bf16x8*)&Kd[sL] = kr0; *(bf16x8*)&Kd[sL + 2048] = kr1;
            *(bf16x8*)&Vd[sL] = vr0; *(bf16x8*)&Vd[sL + 2048] = vr1;
        }
        __syncthreads();
    }

    // --- ONE cross-lane reduction of the denominator (16 lanes) ---
    float l_i[4];
    #pragma unroll
    for (int r = 0; r < 4; r++) {
        float s = l_part[r];
        #pragma unroll
        for (int off = 1; off < 16; off <<= 1) s += __shfl_xor(s, off);
        l_i[r] = s;
    }

    // --- epilogue: context ---
    const float hwf = hw[h];
    float invl[4];
    #pragma unroll
    for (int r = 0; r < 4; r++) invl[r] = hwf / l_i[r];

    #pragma unroll
    for (int db = 0; db < 4; db++)
        #pragma unroll
        for (int r = 0; r < 4; r++) {
            const int qrow = q0 + quad * 4 + r;
            ctx[((size_t)(b * S_ + qrow)) * HID_ + h * HD_ + db * 16 + l16] =
                oacc[db][r] * invl[r];
        }

    // per-row l for the probs kernel
    if (qb >= 30 && l16 == 0) {
        #pragma unroll
        for (int r = 0; r < 4; r++) {
            const int qrow = q0 + quad * 4 + r;
            ml[bh * 128 + (qrow - 1920)] = l_i[r];
        }
    }
}

// ---------------------------------------------------------------------------
// Stage 3: probs — recompute QK^T for the last 128 q rows and write
// NORMALIZED probs directly (single 33.5 MB write; K is L2/L3-resident).
// Grid (8,16,2): x = row-tile(2) x key-quarter(4). Block = 4 waves x 16 rows.
// ---------------------------------------------------------------------------
__global__ __launch_bounds__(256) void probs_qk(
    const u16* __restrict__ Q, const u16* __restrict__ K,
    const float* __restrict__ mask, const float* __restrict__ hw,
    const unsigned* __restrict__ mflag, const float* __restrict__ ml,
    float* __restrict__ probs_out)
{
    const int usemask = (mflag[0] != 0);

    const int tid  = threadIdx.x;
    const int wave = tid >> 6;
    const int lane = tid & 63;
    const int l16  = lane & 15;
    const int quad = lane >> 4;

    const int rt = blockIdx.x & 1;          // row-tile (64 rows)
    const int ks = blockIdx.x >> 1;         // key-quarter (512 keys)
    const int h  = blockIdx.y;
    const int b  = blockIdx.z;
    const int bh = b * NH_ + h;

    const u16* Qh = Q + (size_t)bh * S_ * HD_;
    const u16* Kh = K + (size_t)bh * S_ * HD_;
    const float* Mb = mask + (size_t)b * S_ * S_;

    const int q0 = 1920 + rt * 64 + wave * 16;

    bf16x8 qf0 = ld8(Qh + (size_t)(q0 + l16) * HD_ + quad * 8);
    bf16x8 qf1 = ld8(Qh + (size_t)(q0 + l16) * HD_ + 32 + quad * 8);

    const float hwf = hw[h];
    float invl[4];
    #pragma unroll
    for (int r = 0; r < 4; r++)
        invl[r] = hwf / ml[bh * 128 + (q0 - 1920) + quad * 4 + r];

    for (int kt = ks * 512; kt < ks * 512 + 512; kt += 64) {
        f32x4 sacc[4] = {};
        #pragma unroll
        for (int nb = 0; nb < 4; nb++) {
            const u16* krow = Kh + (size_t)(kt + nb * 16 + l16) * HD_ + quad * 8;
            bf16x8 k0 = ld8(krow);
            bf16x8 k1 = ld8(krow + 32);
            sacc[nb] = __builtin_amdgcn_mfma_f32_16x16x32_bf16(qf0, k0, sacc[nb], 0, 0, 0);
            sacc[nb] = __builtin_amdgcn_mfma_f32_16x16x32_bf16(qf1, k1, sacc[nb], 0, 0, 0);
        }
        #pragma unroll
        for (int nb = 0; nb < 4; nb++)
            #pragma unroll
            for (int r = 0; r < 4; r++) {
                const int qrow = q0 + quad * 4 + r;
                const int key  = kt + nb * 16 + l16;
                float s = sacc[nb][r] * SCALE_;
                if (usemask) s += Mb[(size_t)qrow * S_ + key];
                probs_out[((size_t)bh * 128 + (qrow - 1920)) * S_ + key] =
                    __expf(fminf(s, 80.f)) * invl[r];
            }
    }
}

// ---------------------------------------------------------------------------
extern "C" void kernel_launch(void* const* d_in, const int* in_sizes, int n_in,
                              void* d_out, int out_size, void* d_ws, size_t ws_size,
                              hipStream_t stream)
{
    const void* X = 0; const void* mask = 0; const void* hw = 0;
    const void* Wm[3] = {0, 0, 0}; const void* bm[3] = {0, 0, 0};
    int wi = 0, bi = 0;
    for (int i = 0; i < n_in; i++) {
        switch (in_sizes[i]) {
            case 4194304: X = d_in[i]; break;
            case 8388608: mask = d_in[i]; break;
            case 1048576: if (wi < 3) Wm[wi++] = d_in[i]; break;
            case 1024:    if (bi < 3) bm[bi++] = d_in[i]; break;
            case 16:      hw = d_in[i]; break;
            default: break;
        }
    }
    if (!X || !mask || wi != 3 || bi != 3 || !hw) {
        X = d_in[0]; mask = d_in[1];
        Wm[0] = d_in[2]; bm[0] = d_in[3];
        Wm[1] = d_in[4]; bm[1] = d_in[5];
        Wm[2] = d_in[6]; bm[2] = d_in[7];
        hw = d_in[8];
    }

    u16* Q  = (u16*)d_ws;                    // 8 MB
    u16* Kw = Q + 4194304ull;                // 8 MB
    u16* Vw = Kw + 4194304ull;               // 8 MB (stored transposed per head)
    u16* Xb = Vw + 4194304ull;               // 8 MB
    u16* Wb = Xb + 4194304ull;               // 6 MB
    unsigned* flag = (unsigned*)(Wb + 3145728ull);   // 4 B @ 38 MB
    float* ml = (float*)(flag + 64);                 // 16 KB (l per probs row)

    float* ctx   = (float*)d_out;
    float* probs = ctx + (size_t)B_ * S_ * HID_;

    hipMemsetAsync(flag, 0, 4, stream);
    mask_scan<<<4096, 256, 0, stream>>>((const unsigned*)mask, flag);
    convert_bf16<<<3584, 256, 0, stream>>>(
        (const float*)X, (const float*)Wm[0], (const float*)Wm[1], (const float*)Wm[2],
        Xb, Wb);

    qkv_mfma<<<dim3(32, 24), dim3(256), 0, stream>>>(
        Xb, Wb, (const float*)bm[0], (const float*)bm[1], (const float*)bm[2],
        Q, Kw, Vw);

    attn<<<dim3(32, 16, 2), dim3(256), 0, stream>>>(
        Q, Kw, Vw, (const float*)mask, (const float*)hw, flag, ctx, ml);

    probs_qk<<<dim3(8, 16, 2), dim3(256), 0, stream>>>(
        Q, Kw, (const float*)mask, (const float*)hw, flag, ml, probs);
}

// Round 5
// 238.818 us; speedup vs baseline: 1.1850x; 1.0420x over previous
//
#include <hip/hip_runtime.h>

typedef unsigned short u16;
typedef __attribute__((ext_vector_type(8))) short bf16x8;   // 8 bf16 = 4 VGPRs
typedef __attribute__((ext_vector_type(4))) float f32x4;

#define B_   2
#define S_   2048
#define HID_ 1024
#define NH_  16
#define HD_  64
#define SCALE_ 0.125f    // 1/sqrt(64)

__device__ __forceinline__ u16 f2bf(float f) {
    union { float f; unsigned int i; } v; v.f = f;
    unsigned int r = v.i + 0x7fffu + ((v.i >> 16) & 1u);   // RNE
    return (u16)(r >> 16);
}
__device__ __forceinline__ bf16x8 ld8(const u16* p) {
    return *reinterpret_cast<const bf16x8*>(p);
}
// packed fp32x2 -> bf16x2 (RNE), src0 in low half
__device__ __forceinline__ unsigned cvtpk(float lo, float hi) {
    unsigned r;
    asm("v_cvt_pk_bf16_f32 %0, %1, %2" : "=v"(r) : "v"(lo), "v"(hi));
    return r;
}
// async global->LDS, 16B per lane; l must be wave-uniform (HW adds lane*16)
__device__ __forceinline__ void gll16(const u16* g, const u16* l) {
    __builtin_amdgcn_global_load_lds(
        (const __attribute__((address_space(1))) unsigned int*)g,
        (__attribute__((address_space(3))) unsigned int*)l, 16, 0, 0);
}

// ---------------------------------------------------------------------------
// Stage 0: fused fp32->bf16 convert (blocks [0,3584)) + mask scan (blocks
// [3584,7680)). One launch instead of two.
// ---------------------------------------------------------------------------
__global__ __launch_bounds__(256) void conv_scan(
    const float* __restrict__ X, const float* __restrict__ W0,
    const float* __restrict__ W1, const float* __restrict__ W2,
    const unsigned* __restrict__ m,
    u16* __restrict__ Xb, u16* __restrict__ Wb, unsigned* __restrict__ flag)
{
    const int bx = blockIdx.x;
    if (bx < 3584) {
        const size_t s = (size_t)bx * 256 + threadIdx.x;
        const float* src; u16* dst; size_t off;
        if (s < 524288) { src = X; dst = Xb; off = s * 8; }
        else {
            const size_t t = s - 524288;
            const int w = (int)(t >> 17);
            off = (t & 131071) * 8;
            src = w == 0 ? W0 : w == 1 ? W1 : W2;
            dst = Wb + (size_t)w * 1048576;
        }
        f32x4 a = *(const f32x4*)(src + off);
        f32x4 b = *(const f32x4*)(src + off + 4);
        bf16x8 r;
        #pragma unroll
        for (int e = 0; e < 4; e++) { r[e] = (short)f2bf(a[e]); r[4 + e] = (short)f2bf(b[e]); }
        *(bf16x8*)(dst + off) = r;
    } else {
        const size_t i = ((size_t)(bx - 3584) * 256 + threadIdx.x) * 8;
        const uint4* p = (const uint4*)(m + i);
        uint4 a = p[0], b = p[1];
        const unsigned M = 0x7fffffffu;
        unsigned v = (a.x & M) | (a.y & M) | (a.z & M) | (a.w & M)
                   | (b.x & M) | (b.y & M) | (b.z & M) | (b.w & M);
        if (v) atomicOr(flag, 1u);
    }
}

// ---------------------------------------------------------------------------
// Stage 1: Y = Xb @ Wb^T + bias (single-buffered gll, R2 structure).
// XCD-aware block swizzle (T1): id%8 = XCD (round-robin dispatch); each XCD
// owns 4 row-blocks x all 24 col-blocks, so its A-panel (1 MB) plus the
// currently-streamed B-blocks fit the 4 MB per-XCD L2 — the 393 MB of
// staging re-reads become L2 hits instead of L3 traffic.
// Epilogue bounces C through LDS for 16B stores; V written transposed.
// ---------------------------------------------------------------------------
#define BK_ 32

__global__ __launch_bounds__(256) void qkv_mfma(
    const u16* __restrict__ Xb, const u16* __restrict__ Wb,
    const float* __restrict__ bq, const float* __restrict__ bk,
    const float* __restrict__ bv,
    u16* __restrict__ Q, u16* __restrict__ K, u16* __restrict__ V)
{
    __shared__ __align__(16) u16 As[128 * BK_];   // 8 KB, linear row-major
    __shared__ __align__(16) u16 Bs[128 * BK_];   // 8 KB

    const int tid  = threadIdx.x;
    const int wave = tid >> 6;
    const int lane = tid & 63;
    const int l16  = lane & 15;
    const int quad = lane >> 4;
    const int wr   = wave >> 1, wc = wave & 1;

    // XCD swizzle: bijective (768 = 8 XCDs x 96): row-block = xcd*4 + (k&3),
    // col-block = k>>2. Same-XCD blocks share a 512-row A stripe.
    const int id  = blockIdx.x + 32 * blockIdx.y;   // 0..767
    const int xcd = id & 7;
    const int kk  = id >> 3;                        // 0..95
    const int i0  = (xcd * 4 + (kk & 3)) * 128;     // 0..31 row-blocks
    const int j0  = (kk >> 2) * 128;                // 0..23 col-blocks

    const int grow = (wave * 64 + lane) >> 2;       // 0..63
    const int gcol = (lane & 3) * 8;
    const u16* ldsA0 = As + wave * 512;             // wave-uniform bases
    const u16* ldsA1 = As + 2048 + wave * 512;
    const u16* ldsB0 = Bs + wave * 512;
    const u16* ldsB1 = Bs + 2048 + wave * 512;

    f32x4 acc[4][4] = {};

    for (int k0 = 0; k0 < HID_; k0 += BK_) {
        __syncthreads();
        gll16(Xb + (size_t)(i0 + grow) * HID_ + k0 + gcol, ldsA0);
        gll16(Xb + (size_t)(i0 + 64 + grow) * HID_ + k0 + gcol, ldsA1);
        gll16(Wb + (size_t)(j0 + grow) * HID_ + k0 + gcol, ldsB0);
        gll16(Wb + (size_t)(j0 + 64 + grow) * HID_ + k0 + gcol, ldsB1);
        __syncthreads();

        bf16x8 af[4], bfr[4];
        #pragma unroll
        for (int mt = 0; mt < 4; mt++)
            af[mt] = ld8(&As[(wr * 64 + mt * 16 + l16) * BK_ + quad * 8]);
        #pragma unroll
        for (int nt = 0; nt < 4; nt++)
            bfr[nt] = ld8(&Bs[(wc * 64 + nt * 16 + l16) * BK_ + quad * 8]);
        #pragma unroll
        for (int mt = 0; mt < 4; mt++)
            #pragma unroll
            for (int nt = 0; nt < 4; nt++)
                acc[mt][nt] = __builtin_amdgcn_mfma_f32_16x16x32_bf16(af[mt], bfr[nt], acc[mt][nt], 0, 0, 0);
    }

    const int which = j0 >> 10;                     // block-uniform
    const float* bias = which == 0 ? bq : which == 1 ? bk : bv;
    u16* Y            = which == 0 ? Q  : which == 1 ? K  : V;

    // bounce buffer: 4 waves x 2048 u16 (4 KB each) reusing As/Bs
    u16* bb = (wave < 2) ? (As + wave * 2048) : (Bs + (wave - 2) * 2048);

    #pragma unroll
    for (int p = 0; p < 2; p++) {
        __syncthreads();
        #pragma unroll
        for (int t2 = 0; t2 < 2; t2++) {
            const int nt = 2 * p + t2;
            const int j  = j0 + wc * 64 + nt * 16 + l16;
            const int jj = j & 1023;
            const float bv_ = bias[jj];
            #pragma unroll
            for (int mt = 0; mt < 4; mt++)
                #pragma unroll
                for (int r = 0; r < 4; r++) {
                    const int row = mt * 16 + quad * 4 + r;   // 0..63
                    const int col = t2 * 16 + l16;            // 0..31
                    const u16 val = f2bf(acc[mt][nt][r] + bv_);
                    if (which == 2)
                        bb[col * 64 + (row ^ ((col & 7) << 3))] = val;      // transposed
                    else
                        bb[row * 32 + (col ^ ((row & 0xC) << 1))] = val;    // row-major
                }
        }
        __syncthreads();
        #pragma unroll
        for (int k = 0; k < 4; k++) {
            const int c = lane + 64 * k;   // 0..255 chunks of this wave's 4 KB
            if (which == 2) {
                const int col  = c >> 3;
                const int row0 = (c & 7) * 8;
                bf16x8 v = ld8(&bb[col * 64 + (row0 ^ ((col & 7) << 3))]);
                const int j  = j0 + wc * 64 + p * 32 + col;
                const int jj = j & 1023;
                const int h = jj >> 6, d = jj & 63;
                const int i = i0 + wr * 64 + row0;
                const int b = i >> 11, s = i & (S_ - 1);
                *(bf16x8*)&Y[((size_t)(b * NH_ + h) * HD_ + d) * S_ + s] = v;
            } else {
                const int row  = c >> 2;
                const int col0 = (c & 3) * 8;
                bf16x8 v = ld8(&bb[row * 32 + (col0 ^ ((row & 0xC) << 1))]);
                const int j  = j0 + wc * 64 + p * 32 + col0;
                const int jj = j & 1023;
                const int h = jj >> 6, d = jj & 63;
                const int i = i0 + wr * 64 + row;
                const int b = i >> 11, s = i & (S_ - 1);
                *(bf16x8*)&Y[(((size_t)(b * NH_ + h) * S_ + s) * HD_) + d] = v;
            }
        }
    }
}

// ---------------------------------------------------------------------------
// Stage 2: attention — unchanged from R4 (verified 80.5 µs).
// ---------------------------------------------------------------------------
__global__ __launch_bounds__(256) void attn(
    const u16* __restrict__ Q, const u16* __restrict__ K, const u16* __restrict__ Vt,
    const float* __restrict__ mask, const float* __restrict__ hw,
    const unsigned* __restrict__ mflag,
    float* __restrict__ ctx, float* __restrict__ ml)
{
    __shared__ __align__(16) u16 Ks[2][64 * 64];   // 16 KB  [key][d], swizzled
    __shared__ __align__(16) u16 Vs[2][64 * 64];   // 16 KB  [d][key], swizzled
    __shared__ __align__(16) u16 Pl[4][16 * 64];   //  8 KB  per-wave P, swizzled

    const int usemask = (mflag[0] != 0);

    const int tid  = threadIdx.x;
    const int wave = tid >> 6;
    const int lane = tid & 63;
    const int l16  = lane & 15;
    const int quad = lane >> 4;
    const int x7   = l16 & 7;

    // XCD-aware remap: 4 whole (b,h) per XCD so K/V^T stay L2-resident.
    const int lin = blockIdx.x + 32 * (blockIdx.y + 16 * blockIdx.z);
    const int xcd = lin & 7, jj = lin >> 3;
    const int qb  = jj & 31;
    const int hb  = xcd * 4 + (jj >> 5);
    const int h   = hb & 15, b = hb >> 4;
    const int bh  = b * NH_ + h;

    const u16* Qh  = Q  + (size_t)bh * S_ * HD_;
    const u16* Kh  = K  + (size_t)bh * S_ * HD_;
    const u16* Vth = Vt + (size_t)bh * HD_ * S_;   // [d][s]
    const float* Mb = mask + (size_t)b * S_ * S_;

    const int q0 = qb * 64 + wave * 16;

    bf16x8 qf0 = ld8(Qh + (size_t)(q0 + l16) * HD_ + quad * 8);
    bf16x8 qf1 = ld8(Qh + (size_t)(q0 + l16) * HD_ + 32 + quad * 8);

    f32x4 oacc[4] = {};
    float l_part[4] = {0.f, 0.f, 0.f, 0.f};

    // staging geometry: thread covers 16B slots {tid, tid+256} of each tile
    const int srow = tid >> 3;
    const int sch  = tid & 7;
    const int ssw  = (sch ^ (srow & 7)) * 8;
    const int sL   = srow * 64 + ssw;

    {   // prologue: stage tile 0
        bf16x8 k0 = ld8(Kh + (size_t)srow * HD_ + sch * 8);
        bf16x8 k1 = ld8(Kh + (size_t)(srow + 32) * HD_ + sch * 8);
        bf16x8 v0 = ld8(Vth + (size_t)srow * S_ + sch * 8);
        bf16x8 v1 = ld8(Vth + (size_t)(srow + 32) * S_ + sch * 8);
        *(bf16x8*)&Ks[0][sL] = k0; *(bf16x8*)&Ks[0][sL + 2048] = k1;
        *(bf16x8*)&Vs[0][sL] = v0; *(bf16x8*)&Vs[0][sL + 2048] = v1;
    }
    __syncthreads();

    for (int t = 0; t < 32; ++t) {
        const int cur = t & 1;
        const int kt  = t * 64;
        const u16* Kb = Ks[cur];
        const u16* Vb = Vs[cur];

        // issue next-tile global loads EARLY
        bf16x8 kr0, kr1, vr0, vr1;
        if (t < 31) {
            const u16* Kg = Kh + (size_t)(kt + 64) * HD_;
            kr0 = ld8(Kg + (size_t)srow * HD_ + sch * 8);
            kr1 = ld8(Kg + (size_t)(srow + 32) * HD_ + sch * 8);
            vr0 = ld8(Vth + (size_t)srow * S_ + kt + 64 + sch * 8);
            vr1 = ld8(Vth + (size_t)(srow + 32) * S_ + kt + 64 + sch * 8);
        }

        // --- S = Q K^T (scaled below) ---
        f32x4 sacc[4] = {};
        __builtin_amdgcn_s_setprio(1);
        #pragma unroll
        for (int nb = 0; nb < 4; nb++) {
            const int base = (nb * 16 + l16) * 64;
            bf16x8 k0 = ld8(&Kb[base + ((quad ^ x7) * 8)]);
            bf16x8 k1 = ld8(&Kb[base + (((quad + 4) ^ x7) * 8)]);
            sacc[nb] = __builtin_amdgcn_mfma_f32_16x16x32_bf16(qf0, k0, sacc[nb], 0, 0, 0);
            sacc[nb] = __builtin_amdgcn_mfma_f32_16x16x32_bf16(qf1, k1, sacc[nb], 0, 0, 0);
        }
        __builtin_amdgcn_s_setprio(0);

        // --- deferred softmax: p = exp(min(s,80)), per-lane l accumulation ---
        float p[4][4];
        if (usemask) {
            #pragma unroll
            for (int nb = 0; nb < 4; nb++)
                #pragma unroll
                for (int r = 0; r < 4; r++) {
                    const int qrow = q0 + quad * 4 + r;
                    const int key  = kt + nb * 16 + l16;
                    float s = sacc[nb][r] * SCALE_ + Mb[(size_t)qrow * S_ + key];
                    p[nb][r] = __expf(fminf(s, 80.f));
                    l_part[r] += p[nb][r];
                }
        } else {
            #pragma unroll
            for (int nb = 0; nb < 4; nb++)
                #pragma unroll
                for (int r = 0; r < 4; r++) {
                    p[nb][r] = __expf(fminf(sacc[nb][r] * SCALE_, 80.f));
                    l_part[r] += p[nb][r];
                }
        }

        // --- P -> bf16 (cvt_pk) -> per-wave LDS (swizzled; wave-local) ---
        {
            char* pbase = (char*)&Pl[wave][0];
            const int r0 = quad * 4;
            #pragma unroll
            for (int nb = 0; nb < 4; nb++) {
                const unsigned w01 = cvtpk(p[nb][0], p[nb][1]);
                const unsigned w23 = cvtpk(p[nb][2], p[nb][3]);
                const int c0 = nb * 32 + l16 * 2;
                *(u16*)(pbase + (r0 + 0) * 128 + (c0 ^ (((r0 + 0) & 7) << 4))) = (u16)w01;
                *(u16*)(pbase + (r0 + 1) * 128 + (c0 ^ (((r0 + 1) & 7) << 4))) = (u16)(w01 >> 16);
                *(u16*)(pbase + (r0 + 2) * 128 + (c0 ^ (((r0 + 2) & 7) << 4))) = (u16)w23;
                *(u16*)(pbase + (r0 + 3) * 128 + (c0 ^ (((r0 + 3) & 7) << 4))) = (u16)(w23 >> 16);
            }
        }

        // --- O += P @ V ---
        __builtin_amdgcn_s_setprio(1);
        #pragma unroll
        for (int kb = 0; kb < 2; kb++) {
            const int c = kb * 4 + quad;
            bf16x8 pf = ld8(&Pl[wave][l16 * 64 + ((c ^ x7) * 8)]);
            #pragma unroll
            for (int db = 0; db < 4; db++) {
                bf16x8 vf = ld8(&Vb[(db * 16 + l16) * 64 + ((c ^ x7) * 8)]);
                oacc[db] = __builtin_amdgcn_mfma_f32_16x16x32_bf16(pf, vf, oacc[db], 0, 0, 0);
            }
        }
        __builtin_amdgcn_s_setprio(0);

        // --- write next tile to the other buffer, then sync ---
        if (t < 31) {
            u16* Kd = Ks[cur ^ 1]; u16* Vd = Vs[cur ^ 1];
            *(bf16x8*)&Kd[sL] = kr0; *(bf16x8*)&Kd[sL + 2048] = kr1;
            *(bf16x8*)&Vd[sL] = vr0; *(bf16x8*)&Vd[sL + 2048] = vr1;
        }
        __syncthreads();
    }

    // --- ONE cross-lane reduction of the denominator (16 lanes) ---
    float l_i[4];
    #pragma unroll
    for (int r = 0; r < 4; r++) {
        float s = l_part[r];
        #pragma unroll
        for (int off = 1; off < 16; off <<= 1) s += __shfl_xor(s, off);
        l_i[r] = s;
    }

    // --- epilogue: context ---
    const float hwf = hw[h];
    float invl[4];
    #pragma unroll
    for (int r = 0; r < 4; r++) invl[r] = hwf / l_i[r];

    #pragma unroll
    for (int db = 0; db < 4; db++)
        #pragma unroll
        for (int r = 0; r < 4; r++) {
            const int qrow = q0 + quad * 4 + r;
            ctx[((size_t)(b * S_ + qrow)) * HID_ + h * HD_ + db * 16 + l16] =
                oacc[db][r] * invl[r];
        }

    // per-row l for the probs kernel
    if (qb >= 30 && l16 == 0) {
        #pragma unroll
        for (int r = 0; r < 4; r++) {
            const int qrow = q0 + quad * 4 + r;
            ml[bh * 128 + (qrow - 1920)] = l_i[r];
        }
    }
}

// ---------------------------------------------------------------------------
// Stage 3: probs — recompute QK^T for the last 128 q rows, SWAPPED operands:
// mfma(K,Q) gives C[key][qrow] (lane = qrow, 4 contiguous keys per reg) so
// probs write as float4 (4 vec stores/iter vs 16 scalar). Same MFMA products,
// bit-identical numerics. Grid (16,16,2): x = row-tile(2) x key-eighth(8).
// ---------------------------------------------------------------------------
__global__ __launch_bounds__(256) void probs_qk(
    const u16* __restrict__ Q, const u16* __restrict__ K,
    const float* __restrict__ mask, const float* __restrict__ hw,
    const unsigned* __restrict__ mflag, const float* __restrict__ ml,
    float* __restrict__ probs_out)
{
    const int usemask = (mflag[0] != 0);

    const int tid  = threadIdx.x;
    const int wave = tid >> 6;
    const int lane = tid & 63;
    const int l16  = lane & 15;
    const int quad = lane >> 4;

    const int rt = blockIdx.x & 1;          // row-tile (64 rows)
    const int ks = blockIdx.x >> 1;         // key-eighth (256 keys)
    const int h  = blockIdx.y;
    const int b  = blockIdx.z;
    const int bh = b * NH_ + h;

    const u16* Qh = Q + (size_t)bh * S_ * HD_;
    const u16* Kh = K + (size_t)bh * S_ * HD_;
    const float* Mb = mask + (size_t)b * S_ * S_;

    const int q0   = 1920 + rt * 64 + wave * 16;
    const int qrow = q0 + l16;              // this lane's q row

    bf16x8 qf0 = ld8(Qh + (size_t)qrow * HD_ + quad * 8);
    bf16x8 qf1 = ld8(Qh + (size_t)qrow * HD_ + 32 + quad * 8);

    const float invl = hw[h] / ml[bh * 128 + (qrow - 1920)];
    float* Prow = probs_out + ((size_t)bh * 128 + (qrow - 1920)) * S_;
    const float* Mrow = Mb + (size_t)qrow * S_;

    for (int kt = ks * 256; kt < ks * 256 + 256; kt += 64) {
        f32x4 sacc[4] = {};
        #pragma unroll
        for (int nb = 0; nb < 4; nb++) {
            const u16* krow = Kh + (size_t)(kt + nb * 16 + l16) * HD_ + quad * 8;
            bf16x8 kA0 = ld8(krow);
            bf16x8 kA1 = ld8(krow + 32);
            sacc[nb] = __builtin_amdgcn_mfma_f32_16x16x32_bf16(kA0, qf0, sacc[nb], 0, 0, 0);
            sacc[nb] = __builtin_amdgcn_mfma_f32_16x16x32_bf16(kA1, qf1, sacc[nb], 0, 0, 0);
        }
        #pragma unroll
        for (int nb = 0; nb < 4; nb++) {
            const int kb0 = kt + nb * 16 + quad * 4;   // 4 contiguous keys
            float4 v;
            if (usemask) {
                const float4 mv = *(const float4*)&Mrow[kb0];
                v.x = __expf(fminf(sacc[nb][0] * SCALE_ + mv.x, 80.f)) * invl;
                v.y = __expf(fminf(sacc[nb][1] * SCALE_ + mv.y, 80.f)) * invl;
                v.z = __expf(fminf(sacc[nb][2] * SCALE_ + mv.z, 80.f)) * invl;
                v.w = __expf(fminf(sacc[nb][3] * SCALE_ + mv.w, 80.f)) * invl;
            } else {
                v.x = __expf(fminf(sacc[nb][0] * SCALE_, 80.f)) * invl;
                v.y = __expf(fminf(sacc[nb][1] * SCALE_, 80.f)) * invl;
                v.z = __expf(fminf(sacc[nb][2] * SCALE_, 80.f)) * invl;
                v.w = __expf(fminf(sacc[nb][3] * SCALE_, 80.f)) * invl;
            }
            *(float4*)&Prow[kb0] = v;
        }
    }
}

// ---------------------------------------------------------------------------
extern "C" void kernel_launch(void* const* d_in, const int* in_sizes, int n_in,
                              void* d_out, int out_size, void* d_ws, size_t ws_size,
                              hipStream_t stream)
{
    const void* X = 0; const void* mask = 0; const void* hw = 0;
    const void* Wm[3] = {0, 0, 0}; const void* bm[3] = {0, 0, 0};
    int wi = 0, bi = 0;
    for (int i = 0; i < n_in; i++) {
        switch (in_sizes[i]) {
            case 4194304: X = d_in[i]; break;
            case 8388608: mask = d_in[i]; break;
            case 1048576: if (wi < 3) Wm[wi++] = d_in[i]; break;
            case 1024:    if (bi < 3) bm[bi++] = d_in[i]; break;
            case 16:      hw = d_in[i]; break;
            default: break;
        }
    }
    if (!X || !mask || wi != 3 || bi != 3 || !hw) {
        X = d_in[0]; mask = d_in[1];
        Wm[0] = d_in[2]; bm[0] = d_in[3];
        Wm[1] = d_in[4]; bm[1] = d_in[5];
        Wm[2] = d_in[6]; bm[2] = d_in[7];
        hw = d_in[8];
    }

    u16* Q  = (u16*)d_ws;                    // 8 MB
    u16* Kw = Q + 4194304ull;                // 8 MB
    u16* Vw = Kw + 4194304ull;               // 8 MB (stored transposed per head)
    u16* Xb = Vw + 4194304ull;               // 8 MB
    u16* Wb = Xb + 4194304ull;               // 6 MB
    unsigned* flag = (unsigned*)(Wb + 3145728ull);   // 4 B @ 38 MB
    float* ml = (float*)(flag + 64);                 // 16 KB (l per probs row)

    float* ctx   = (float*)d_out;
    float* probs = ctx + (size_t)B_ * S_ * HID_;

    hipMemsetAsync(flag, 0, 4, stream);
    conv_scan<<<7680, 256, 0, stream>>>(
        (const float*)X, (const float*)Wm[0], (const float*)Wm[1], (const float*)Wm[2],
        (const unsigned*)mask, Xb, Wb, flag);

    qkv_mfma<<<dim3(32, 24), dim3(256), 0, stream>>>(
        Xb, Wb, (const float*)bm[0], (const float*)bm[1], (const float*)bm[2],
        Q, Kw, Vw);

    attn<<<dim3(32, 16, 2), dim3(256), 0, stream>>>(
        Q, Kw, Vw, (const float*)mask, (const float*)hw, flag, ctx, ml);

    probs_qk<<<dim3(16, 16, 2), dim3(256), 0, stream>>>(
        Q, Kw, (const float*)mask, (const float*)hw, flag, ml, probs);
}